// Round 1
// baseline (977.202 us; speedup 1.0000x reference)
//
#include <hip/hip_runtime.h>

// Problem constants (from setup_inputs):
//   img:  (B=8, C=256, H=128, W=128) fp32
//   W:    (E=1024, C=256, K=2, K=2)  fp32  -> per-e row of 1024 contiguous k=(c,ky,kx)
//   b:    (E=1024,) fp32
//   ids:  (8,512) int32
//   out:  (B=8, 4E=4096, N=512) fp32, out[b][off*1024+e][n]
//   off order: (dy,dx) = (0,0),(2,0),(0,2),(2,2); img row = y0+dy+ky-1, col = x0+dx+kx-1

#define TILE_E 64
#define TILE_N 64
#define KCHUNK 64
#define LSTR   68   // LDS row stride (floats): 16B-aligned for float4, breaks pow2 conflicts

__global__ __launch_bounds__(256, 4)
void i2f_gemm(const float* __restrict__ img,
              const float* __restrict__ Wmat,
              const float* __restrict__ bias,
              const int*   __restrict__ bidx,
              const int*   __restrict__ pxid,
              const int*   __restrict__ pyid,
              float*       __restrict__ out)
{
    const int bid = blockIdx.x;
    const int nt  = bid & 7;          // 8 n-tiles of 64  (N=512)
    const int et  = (bid >> 3) & 15;  // 16 e-tiles of 64 (E=1024)
    const int off = (bid >> 7) & 3;   // 4 offsets
    const int b   = bid >> 9;         // 8 batches
    const int dy  = (off & 1) * 2;    // samp order: (0,0),(K,0),(0,K),(K,K)
    const int dx  = (off >> 1) * 2;
    const int e0  = et * TILE_E;
    const int n0  = nt * TILE_N;
    const int tid = threadIdx.x;

    __shared__ float sWT[KCHUNK][LSTR];  // [k][e]  (transposed W tile)
    __shared__ float sA [KCHUNK][LSTR];  // [k][n]  (gathered img tile)
    __shared__ int   sY[TILE_N], sX[TILE_N], sB[TILE_N];

    if (tid < TILE_N) {
        const int n  = n0 + tid;
        const int gi = b * 512 + n;
        sY[tid] = 2 * pyid[gi] + dy - 1;   // base img row for ky=0
        sX[tid] = 2 * pxid[gi] + dx - 1;   // base img col for kx=0
        sB[tid] = bidx[gi];
    }
    __syncthreads();

    float acc[4][4] = {};                 // [e_sub][n_sub]

    const int fq = tid & 15;              // W-load: k sub-index
    const int er = tid >> 4;              // W-load: e sub-index (0..15)
    const int nl = tid & 63;              // A-load: n within tile
    const int kr = tid >> 6;              // A-load: k phase (0..3)
    const int tx = tid & 15;              // compute: e-quad
    const int ty = tid >> 4;              // compute: n-quad

    // Hoist per-thread gather bases
    const int ybase = sY[nl];
    const int xbase = sX[nl];
    const size_t plane_base = (size_t)sB[nl] * 256 * 128 * 128;

    for (int kc = 0; kc < 16; ++kc) {
        const int k0 = kc * KCHUNK;

        // ---- stage W tile (transposed): sWT[k][e] ----
        // lanes 0..15 read 16 consecutive floats (64B coalesced segments);
        // LDS write bank = (4*fq + e) % 32 -> 2-way max (free).
        #pragma unroll
        for (int r = 0; r < 4; ++r) {
            const int e = er + 16 * r;
            const float* wrow = &Wmat[(size_t)(e0 + e) * 1024 + k0];
            #pragma unroll
            for (int u = 0; u < 4; ++u) {
                const int kk = fq + 16 * u;
                sWT[kk][e] = wrow[kk];
            }
        }

        // ---- stage A tile (gather): sA[k][n] ----
        #pragma unroll
        for (int r = 0; r < 16; ++r) {
            const int kk = kr + 4 * r;    // 0..63
            const int k  = k0 + kk;
            const int c  = k >> 2;
            const int ky = (k >> 1) & 1;
            const int kx = k & 1;
            const int y  = ybase + ky;
            const int x  = xbase + kx;
            float v = 0.0f;
            if ((unsigned)y < 128u && (unsigned)x < 128u)
                v = img[plane_base + ((size_t)c * 128 + y) * 128 + x];
            sA[kk][nl] = v;
        }

        __syncthreads();

        // ---- 64x64x64 fp32 FMA tile: each thread does 4x4 ----
        #pragma unroll 8
        for (int kk = 0; kk < KCHUNK; ++kk) {
            const float4 wv = *(const float4*)&sWT[kk][tx * 4];
            const float4 av = *(const float4*)&sA [kk][ty * 4];
            const float we[4] = {wv.x, wv.y, wv.z, wv.w};
            const float ae[4] = {av.x, av.y, av.z, av.w};
            #pragma unroll
            for (int i = 0; i < 4; ++i)
                #pragma unroll
                for (int j = 0; j < 4; ++j)
                    acc[i][j] = fmaf(we[i], ae[j], acc[i][j]);
        }

        __syncthreads();
    }

    // ---- epilogue: add bias, write float4 along n ----
    #pragma unroll
    for (int i = 0; i < 4; ++i) {
        const int e = e0 + tx * 4 + i;
        const float bv = bias[e];
        float4 v;
        v.x = acc[i][0] + bv;
        v.y = acc[i][1] + bv;
        v.z = acc[i][2] + bv;
        v.w = acc[i][3] + bv;
        const size_t row = (size_t)b * 4096 + (size_t)off * 1024 + e;
        *(float4*)&out[row * 512 + n0 + ty * 4] = v;
    }
}

extern "C" void kernel_launch(void* const* d_in, const int* in_sizes, int n_in,
                              void* d_out, int out_size, void* d_ws, size_t ws_size,
                              hipStream_t stream) {
    const float* img  = (const float*)d_in[0];
    const float* Wmat = (const float*)d_in[1];
    const float* bias = (const float*)d_in[2];
    const int*   bidx = (const int*)d_in[3];
    const int*   pxid = (const int*)d_in[4];
    const int*   pyid = (const int*)d_in[5];
    float* out = (float*)d_out;

    // 8 b * 4 off * 16 e-tiles * 8 n-tiles = 4096 blocks
    dim3 grid(4096), block(256);
    hipLaunchKernelGGL(i2f_gemm, grid, block, 0, stream,
                       img, Wmat, bias, bidx, pxid, pyid, out);
}

// Round 2
// 131.161 us; speedup vs baseline: 7.4504x; 7.4504x over previous
//
#include <hip/hip_runtime.h>
#include <stdint.h>

// Problem:
//   img:  (8, 256, 128, 128) fp32
//   W:    (1024, 256, 2, 2)  fp32  -> row e has 1024 contiguous k=(c,ky,kx)
//   b:    (1024,) fp32
//   ids:  (8,512) int (harness downcasts int64->int32)
//   out:  (8, 4096, 512) fp32; out[b][off*1024+e][n], flat=((b*4+off)*1024+e)*512+n
// Restructure: A[g][n][k] gathered once (g=b*4+off), then 32 fused GEMMs
//   C[e][g,n] = sum_k W[e][k] * A[g][n][k]  (+bias[e]) via bf16 MFMA.

typedef __attribute__((ext_vector_type(8))) short bf16x8;
typedef __attribute__((ext_vector_type(4))) float f32x4;

#define GAS(p) ((const __attribute__((address_space(1))) void*)(p))
#define LAS(p) ((__attribute__((address_space(3))) void*)(p))

__device__ __forceinline__ unsigned short f2bf(float f) {
    union { float f; uint32_t u; } x; x.f = f;
    uint32_t u = x.u;
    uint32_t r = (u + 0x7FFFu + ((u >> 16) & 1u)) >> 16;   // round-nearest-even
    return (unsigned short)r;
}

// ---------------- Stage 0: W fp32 -> bf16 ----------------
__global__ __launch_bounds__(256)
void wconv_kernel(const float* __restrict__ Wf, unsigned short* __restrict__ Wbf) {
    const int i = (blockIdx.x * 256 + threadIdx.x) * 4;   // 1024 blocks covers 1M
    float4 v = *(const float4*)&Wf[i];
    ushort4 o;
    o.x = f2bf(v.x); o.y = f2bf(v.y); o.z = f2bf(v.z); o.w = f2bf(v.w);
    *(ushort4*)&Wbf[i] = o;
}

// ---------------- Stage 1: gather A[g][n][k] in bf16 ----------------
// block = (b, n); thread = channel c. Each thread reads its 4x4 patch
// (each pixel used exactly once across the 4 offsets) and writes 4x ushort4.
__global__ __launch_bounds__(256)
void gather_kernel(const float* __restrict__ img,
                   const int* __restrict__ bidx,
                   const int* __restrict__ pxid,
                   const int* __restrict__ pyid,
                   unsigned short* __restrict__ Abf) {
    const int blk = blockIdx.x;           // 0..4095
    const int b = blk >> 9, n = blk & 511;
    const int c = threadIdx.x;
    const int gi = b * 512 + n;
    const int bi = bidx[gi];
    const int y0 = 2 * pyid[gi] - 1;      // img row for patch py=0
    const int x0 = 2 * pxid[gi] - 1;
    const float* base = img + ((size_t)bi * 256 + c) * (128 * 128);

    float p[4][4];
    #pragma unroll
    for (int py = 0; py < 4; ++py) {
        const int y = y0 + py;
        const bool yok = ((unsigned)y < 128u);
        #pragma unroll
        for (int px = 0; px < 4; ++px) {
            const int x = x0 + px;
            p[py][px] = (yok && (unsigned)x < 128u) ? base[y * 128 + x] : 0.0f;
        }
    }

    #pragma unroll
    for (int o = 0; o < 4; ++o) {
        const int dy = 2 * (o & 1);       // samp order (0,0),(K,0),(0,K),(K,K)
        const int dx = 2 * (o >> 1);
        ushort4 v;
        v.x = f2bf(p[dy + 0][dx + 0]);    // k=(ky=0,kx=0)
        v.y = f2bf(p[dy + 0][dx + 1]);    // (0,1)
        v.z = f2bf(p[dy + 1][dx + 0]);    // (1,0)
        v.w = f2bf(p[dy + 1][dx + 1]);    // (1,1)
        const size_t row = ((size_t)(b * 4 + o) * 512 + n);
        *(ushort4*)&Abf[row * 1024 + c * 4] = v;   // 8B contiguous across lanes
    }
}

// ---------------- Stage 2: bf16 MFMA GEMM ----------------
// C[1024 e][16384 gn], 128x128 tiles, BK=64, 4 waves (2x2), 16x16x32 MFMA.
// LDS tiles [128 rows][8 x 16B chunks], XOR swizzle: phys chunk = logical ^ (row&7),
// applied on the global SOURCE address (global_load_lds writes linearly) and on ds_read.
__global__ __launch_bounds__(256)
void gemm_kernel(const unsigned short* __restrict__ Wbf,
                 const unsigned short* __restrict__ Abf,
                 const float* __restrict__ bias,
                 float* __restrict__ out) {
    const int orig = blockIdx.x;                 // 1024 blocks
    const int wg = (orig & 7) * 128 + (orig >> 3);  // bijective XCD swizzle (1024%8==0)
    const int et = wg & 7;                       // 8 e-tiles of 128
    const int nt = wg >> 3;                      // 128 n-tiles of 128
    const int g  = nt >> 2;                      // 32 groups (b*4+off)
    const int n0 = (nt & 3) * 128;
    const int e0 = et * 128;

    const int tid  = threadIdx.x;
    const int lane = tid & 63;
    const int wid  = tid >> 6;
    const int wr   = wid >> 1;                   // wave row (e half)
    const int wc   = wid & 1;                    // wave col (n half)

    __shared__ unsigned short sW[128 * 64];      // 16 KB, rows of 128B (8 chunks)
    __shared__ unsigned short sA[128 * 64];      // 16 KB

    const f32x4 fzero = {0.f, 0.f, 0.f, 0.f};
    f32x4 acc[4][4];
    #pragma unroll
    for (int m = 0; m < 4; ++m)
        #pragma unroll
        for (int nf = 0; nf < 4; ++nf) acc[m][nf] = fzero;

    // staging decomposition: i = r*256+tid in [0,1024): row=i>>3, phys chunk cl=i&7
    const size_t wrow_base = (size_t)e0 * 1024;
    const size_t arow_base = ((size_t)g * 512 + n0) * 1024;

    for (int kc = 0; kc < 16; ++kc) {
        if (kc) __syncthreads();                 // protect LDS from prev compute
        const int kbase = kc * 64;
        #pragma unroll
        for (int r = 0; r < 4; ++r) {
            const int i   = r * 256 + tid;
            const int row = i >> 3;
            const int cl  = i & 7;
            const int cg  = cl ^ (row & 7);      // pre-swizzled global chunk
            const unsigned short* gw = Wbf + wrow_base + (size_t)row * 1024 + kbase + cg * 8;
            __builtin_amdgcn_global_load_lds(GAS(gw), LAS(&sW[i * 8]), 16, 0, 0);
            const unsigned short* ga = Abf + arow_base + (size_t)row * 1024 + kbase + cg * 8;
            __builtin_amdgcn_global_load_lds(GAS(ga), LAS(&sA[i * 8]), 16, 0, 0);
        }
        asm volatile("s_waitcnt vmcnt(0)" ::: "memory");
        __syncthreads();

        #pragma unroll
        for (int ks = 0; ks < 2; ++ks) {
            bf16x8 af[4], bfr[4];
            #pragma unroll
            for (int m = 0; m < 4; ++m) {
                const int row = wr * 64 + m * 16 + (lane & 15);
                const int cgc = ks * 4 + (lane >> 4);
                const int cl  = cgc ^ (row & 7);
                af[m] = *(const bf16x8*)&sW[row * 64 + cl * 8];
            }
            #pragma unroll
            for (int nf = 0; nf < 4; ++nf) {
                const int row = wc * 64 + nf * 16 + (lane & 15);
                const int cgc = ks * 4 + (lane >> 4);
                const int cl  = cgc ^ (row & 7);
                bfr[nf] = *(const bf16x8*)&sA[row * 64 + cl * 8];
            }
            #pragma unroll
            for (int m = 0; m < 4; ++m)
                #pragma unroll
                for (int nf = 0; nf < 4; ++nf)
                    acc[m][nf] = __builtin_amdgcn_mfma_f32_16x16x32_bf16(
                        af[m], bfr[nf], acc[m][nf], 0, 0, 0);
        }
    }

    // epilogue: D row = (lane>>4)*4 + reg (e), col = lane&15 (n)
    const int erow_l = (lane >> 4) * 4;
    const int ncol_l = lane & 15;
    #pragma unroll
    for (int m = 0; m < 4; ++m) {
        #pragma unroll
        for (int nf = 0; nf < 4; ++nf) {
            const int nn = n0 + wc * 64 + nf * 16 + ncol_l;
            #pragma unroll
            for (int reg = 0; reg < 4; ++reg) {
                const int e = e0 + wr * 64 + m * 16 + erow_l + reg;
                out[((size_t)g * 1024 + e) * 512 + nn] = acc[m][nf][reg] + bias[e];
            }
        }
    }
}

extern "C" void kernel_launch(void* const* d_in, const int* in_sizes, int n_in,
                              void* d_out, int out_size, void* d_ws, size_t ws_size,
                              hipStream_t stream) {
    const float* img  = (const float*)d_in[0];
    const float* Wf   = (const float*)d_in[1];
    const float* bias = (const float*)d_in[2];
    const int*   bidx = (const int*)d_in[3];
    const int*   pxid = (const int*)d_in[4];
    const int*   pyid = (const int*)d_in[5];
    float* out = (float*)d_out;

    unsigned short* Abf = (unsigned short*)d_ws;                       // 32 MiB
    unsigned short* Wbf = (unsigned short*)((char*)d_ws + (32u << 20)); // 2 MiB

    hipLaunchKernelGGL(wconv_kernel, dim3(1024), dim3(256), 0, stream, Wf, Wbf);
    hipLaunchKernelGGL(gather_kernel, dim3(4096), dim3(256), 0, stream,
                       img, bidx, pxid, pyid, Abf);
    hipLaunchKernelGGL(gemm_kernel, dim3(1024), dim3(256), 0, stream,
                       Wbf, Abf, bias, out);
}

// Round 3
// 123.287 us; speedup vs baseline: 7.9262x; 1.0639x over previous
//
#include <hip/hip_runtime.h>
#include <stdint.h>

// Problem:
//   img:  (8, 256, 128, 128) fp32
//   W:    (1024, 256, 2, 2)  fp32  -> row e has 1024 contiguous k=(c,ky,kx)
//   b:    (1024,) fp32
//   ids:  (8,512) int32 (harness downcast)
//   out:  (8, 4096, 512) fp32; flat=((b*4+off)*1024+e)*512+n
// Pipeline: Wconv (fp32->bf16), Gather A[g][n][k] bf16 (g=b*4+off), MFMA GEMM.

typedef __attribute__((ext_vector_type(8))) short bf16x8;
typedef __attribute__((ext_vector_type(4))) float f32x4;

#define GAS(p) ((const __attribute__((address_space(1))) void*)(p))
#define LAS(p) ((__attribute__((address_space(3))) void*)(p))

__device__ __forceinline__ unsigned short f2bf(float f) {
    union { float f; uint32_t u; } x; x.f = f;
    uint32_t u = x.u;
    uint32_t r = (u + 0x7FFFu + ((u >> 16) & 1u)) >> 16;   // round-nearest-even
    return (unsigned short)r;
}

// ---------------- Stage 0: W fp32 -> bf16 ----------------
__global__ __launch_bounds__(256)
void wconv_kernel(const float* __restrict__ Wf, unsigned short* __restrict__ Wbf) {
    const int i = (blockIdx.x * 256 + threadIdx.x) * 4;
    float4 v = *(const float4*)&Wf[i];
    ushort4 o;
    o.x = f2bf(v.x); o.y = f2bf(v.y); o.z = f2bf(v.z); o.w = f2bf(v.w);
    *(ushort4*)&Wbf[i] = o;
}

// ---------------- Stage 1: gather A[g][n][k] in bf16 ----------------
// block = one keypoint (b,n). Phase 1: thread (c4,py,px) loads pixel
// (y0+py, x0+px) for channels c = ci*16+c4 — the 4 px-lanes are CONTIGUOUS
// floats, so a wave-instruction touches ~16 lines instead of 64.
// Phase 2: LDS transpose -> coalesced ushort4 writes per offset.
__global__ __launch_bounds__(256)
void gather_kernel(const float* __restrict__ img,
                   const int* __restrict__ bidx,
                   const int* __restrict__ pxid,
                   const int* __restrict__ pyid,
                   unsigned short* __restrict__ Abf) {
    const int blk = blockIdx.x;           // 0..4095
    const int b = blk >> 9, n = blk & 511;
    const int gi = b * 512 + n;
    const int bi = bidx[gi];
    const int y0 = 2 * pyid[gi] - 1;      // img row for patch py=0
    const int x0 = 2 * pxid[gi] - 1;

    __shared__ unsigned short sP[256 * 16];   // [c][py][px], 8 KB

    const int tid = threadIdx.x;
    const int c4 = tid >> 4;              // 0..15
    const int py = (tid >> 2) & 3;
    const int px = tid & 3;
    const int y  = y0 + py;
    const int x  = x0 + px;
    const bool ok = ((unsigned)y < 128u) && ((unsigned)x < 128u);
    const float* base = img + (size_t)bi * (256 * 128 * 128) + y * 128 + x;

    #pragma unroll
    for (int ci = 0; ci < 16; ++ci) {
        const int c = ci * 16 + c4;
        float v = ok ? base[(size_t)c * (128 * 128)] : 0.0f;
        sP[c * 16 + py * 4 + px] = f2bf(v);   // linear in tid -> conflict-free
    }
    __syncthreads();

    // Phase 2: thread = c; for each offset pack k=(ky,kx) and write ushort4.
    const int c = tid;
    #pragma unroll
    for (int o = 0; o < 4; ++o) {
        const int dy = 2 * (o & 1);       // samp order (0,0),(K,0),(0,K),(K,K)
        const int dx = 2 * (o >> 1);
        ushort4 v;
        v.x = sP[c * 16 + (dy + 0) * 4 + (dx + 0)];
        v.y = sP[c * 16 + (dy + 0) * 4 + (dx + 1)];
        v.z = sP[c * 16 + (dy + 1) * 4 + (dx + 0)];
        v.w = sP[c * 16 + (dy + 1) * 4 + (dx + 1)];
        const size_t row = ((size_t)(b * 4 + o) * 512 + n);
        *(ushort4*)&Abf[row * 1024 + c * 4] = v;   // 8B/lane contiguous
    }
}

// ---------------- Stage 2: bf16 MFMA GEMM ----------------
// C[1024 e][16384 gn], 128x128 tiles, BK=64, 4 waves (2x2), 16x16x32 MFMA.
// LDS tiles [128 rows][8 x 16B chunks], XOR swizzle on global SOURCE + ds_read.
__global__ __launch_bounds__(256)
void gemm_kernel(const unsigned short* __restrict__ Wbf,
                 const unsigned short* __restrict__ Abf,
                 const float* __restrict__ bias,
                 float* __restrict__ out) {
    const int orig = blockIdx.x;                 // 1024 blocks
    const int wg = (orig & 7) * 128 + (orig >> 3);  // bijective XCD swizzle
    const int et = wg & 7;                       // 8 e-tiles of 128
    const int nt = wg >> 3;                      // 128 gn-tiles of 128
    const int g  = nt >> 2;
    const int n0 = (nt & 3) * 128;
    const int e0 = et * 128;

    const int tid  = threadIdx.x;
    const int lane = tid & 63;
    const int wid  = tid >> 6;
    const int wr   = wid >> 1;
    const int wc   = wid & 1;

    __shared__ unsigned short sW[128 * 64];
    __shared__ unsigned short sA[128 * 64];

    const f32x4 fzero = {0.f, 0.f, 0.f, 0.f};
    f32x4 acc[4][4];
    #pragma unroll
    for (int m = 0; m < 4; ++m)
        #pragma unroll
        for (int nf = 0; nf < 4; ++nf) acc[m][nf] = fzero;

    const size_t wrow_base = (size_t)e0 * 1024;
    const size_t arow_base = ((size_t)g * 512 + n0) * 1024;

    for (int kc = 0; kc < 16; ++kc) {
        if (kc) __syncthreads();
        const int kbase = kc * 64;
        #pragma unroll
        for (int r = 0; r < 4; ++r) {
            const int i   = r * 256 + tid;
            const int row = i >> 3;
            const int cl  = i & 7;
            const int cg  = cl ^ (row & 7);      // pre-swizzled global chunk
            const unsigned short* gw = Wbf + wrow_base + (size_t)row * 1024 + kbase + cg * 8;
            __builtin_amdgcn_global_load_lds(GAS(gw), LAS(&sW[i * 8]), 16, 0, 0);
            const unsigned short* ga = Abf + arow_base + (size_t)row * 1024 + kbase + cg * 8;
            __builtin_amdgcn_global_load_lds(GAS(ga), LAS(&sA[i * 8]), 16, 0, 0);
        }
        asm volatile("s_waitcnt vmcnt(0)" ::: "memory");
        __syncthreads();

        #pragma unroll
        for (int ks = 0; ks < 2; ++ks) {
            bf16x8 af[4], bfr[4];
            #pragma unroll
            for (int m = 0; m < 4; ++m) {
                const int row = wr * 64 + m * 16 + (lane & 15);
                const int cgc = ks * 4 + (lane >> 4);
                const int cl  = cgc ^ (row & 7);
                af[m] = *(const bf16x8*)&sW[row * 64 + cl * 8];
            }
            #pragma unroll
            for (int nf = 0; nf < 4; ++nf) {
                const int row = wc * 64 + nf * 16 + (lane & 15);
                const int cgc = ks * 4 + (lane >> 4);
                const int cl  = cgc ^ (row & 7);
                bfr[nf] = *(const bf16x8*)&sA[row * 64 + cl * 8];
            }
            #pragma unroll
            for (int m = 0; m < 4; ++m)
                #pragma unroll
                for (int nf = 0; nf < 4; ++nf)
                    acc[m][nf] = __builtin_amdgcn_mfma_f32_16x16x32_bf16(
                        af[m], bfr[nf], acc[m][nf], 0, 0, 0);
        }
    }

    const int erow_l = (lane >> 4) * 4;
    const int ncol_l = lane & 15;
    #pragma unroll
    for (int m = 0; m < 4; ++m) {
        #pragma unroll
        for (int nf = 0; nf < 4; ++nf) {
            const int nn = n0 + wc * 64 + nf * 16 + ncol_l;
            #pragma unroll
            for (int reg = 0; reg < 4; ++reg) {
                const int e = e0 + wr * 64 + m * 16 + erow_l + reg;
                out[((size_t)g * 1024 + e) * 512 + nn] = acc[m][nf][reg] + bias[e];
            }
        }
    }
}

extern "C" void kernel_launch(void* const* d_in, const int* in_sizes, int n_in,
                              void* d_out, int out_size, void* d_ws, size_t ws_size,
                              hipStream_t stream) {
    const float* img  = (const float*)d_in[0];
    const float* Wf   = (const float*)d_in[1];
    const float* bias = (const float*)d_in[2];
    const int*   bidx = (const int*)d_in[3];
    const int*   pxid = (const int*)d_in[4];
    const int*   pyid = (const int*)d_in[5];
    float* out = (float*)d_out;

    unsigned short* Abf = (unsigned short*)d_ws;                        // 32 MiB
    unsigned short* Wbf = (unsigned short*)((char*)d_ws + (32u << 20)); // 2 MiB

    hipLaunchKernelGGL(wconv_kernel, dim3(1024), dim3(256), 0, stream, Wf, Wbf);
    hipLaunchKernelGGL(gather_kernel, dim3(4096), dim3(256), 0, stream,
                       img, bidx, pxid, pyid, Abf);
    hipLaunchKernelGGL(gemm_kernel, dim3(1024), dim3(256), 0, stream,
                       Wbf, Abf, bias, out);
}

// Round 4
// 102.648 us; speedup vs baseline: 9.5199x; 1.2011x over previous
//
#include <hip/hip_runtime.h>
#include <stdint.h>

// Pipeline (k' = (ky*2+kx)*256 + c ordering for the GEMM K axis):
//   0. wconv : W (1024,256,2,2) fp32 -> W'[e][p*256+c] bf16           (2 MiB)
//   1. imgt  : img (8,256,128,128) fp32 -> imgT[b][y][x][c] bf16      (64 MiB)
//   2. gather: per keypoint copy 16 pixel c-vectors -> A[g][n][k']    (32 MiB)
//      (pixel (py,px) -> offset o=(py>>1)+2*(px>>1), pos p=(py&1)*2+(px&1): bijective)
//   3. gemm  : out[(g*1024+e)][n] = sum_k' W'[e][k'] * A[g][n][k'] + bias[e]

typedef __attribute__((ext_vector_type(8))) short bf16x8;
typedef __attribute__((ext_vector_type(4))) float f32x4;

#define GAS(p) ((const __attribute__((address_space(1))) void*)(p))
#define LAS(p) ((__attribute__((address_space(3))) void*)(p))

__device__ __forceinline__ unsigned short f2bf(float f) {
    union { float f; uint32_t u; } x; x.f = f;
    uint32_t u = x.u;
    uint32_t r = (u + 0x7FFFu + ((u >> 16) & 1u)) >> 16;   // round-nearest-even
    return (unsigned short)r;
}

// ---------------- Stage 0: W reorder fp32 -> bf16, k = c*4+p -> k' = p*256+c ----
__global__ __launch_bounds__(256)
void wconv_kernel(const float* __restrict__ Wf, unsigned short* __restrict__ Wp) {
    const int e = blockIdx.x;            // 1024
    const int c = threadIdx.x;           // 256
    float4 w4 = *(const float4*)&Wf[(size_t)e * 1024 + c * 4];  // (ky,kx)=(0,0),(0,1),(1,0),(1,1)
    Wp[e * 1024 + 0 * 256 + c] = f2bf(w4.x);
    Wp[e * 1024 + 1 * 256 + c] = f2bf(w4.y);
    Wp[e * 1024 + 2 * 256 + c] = f2bf(w4.z);
    Wp[e * 1024 + 3 * 256 + c] = f2bf(w4.w);
}

// ---------------- Stage 1: img -> imgT[b][y][x][c] bf16 ----------------
// block = (b, y, c-chunk of 64). Reads x-coalesced scalar pairs, LDS transpose
// (XOR swizzle, conflict-free both phases), writes c-coalesced uint chunks.
__global__ __launch_bounds__(256)
void imgt_kernel(const float* __restrict__ img, unsigned short* __restrict__ imgT) {
    const int blk = blockIdx.x;          // 4096
    const int cc = blk & 3;
    const int y  = (blk >> 2) & 127;
    const int b  = blk >> 9;
    __shared__ unsigned short sT[8192];  // [x:128][c:64] swizzled, 16 KB
    const int t  = threadIdx.x;
    const int x  = t & 127;
    const int ah = t >> 7;               // 0..1
    const size_t ibase = ((size_t)b * 256 + cc * 64) * 16384 + (size_t)y * 128 + x;
    #pragma unroll
    for (int it = 0; it < 16; ++it) {
        const int a = ah + 2 * it;       // c-pair 0..31
        const float v0 = img[ibase + (size_t)(2 * a)     * 16384];
        const float v1 = img[ibase + (size_t)(2 * a + 1) * 16384];
        const unsigned int pk = (unsigned)f2bf(v0) | ((unsigned)f2bf(v1) << 16);
        *(unsigned int*)&sT[x * 64 + ((2 * a) ^ (2 * (x & 31)))] = pk;
    }
    __syncthreads();
    unsigned short* ob = imgT + (((size_t)b * 128 + y) * 128) * 256 + cc * 64;
    #pragma unroll
    for (int jj = 0; jj < 16; ++jj) {
        const int o  = t + 256 * jj;     // 0..4095
        const int xx = o >> 5;
        const int c2 = o & 31;
        const unsigned int pk = *(const unsigned int*)&sT[xx * 64 + 2 * (c2 ^ (xx & 31))];
        *(unsigned int*)&ob[(size_t)xx * 256 + c2 * 2] = pk;
    }
}

// ---------------- Stage 2: gather A[g][n][k'] — pure coalesced copy ----------------
__global__ __launch_bounds__(256)
void gather_kernel(const unsigned short* __restrict__ imgT,
                   const int* __restrict__ bidx,
                   const int* __restrict__ pxid,
                   const int* __restrict__ pyid,
                   unsigned short* __restrict__ Abf) {
    const int blk = blockIdx.x;          // 4096 keypoints
    const int b = blk >> 9, n = blk & 511;
    const int gi = b * 512 + n;
    const int bi = bidx[gi];
    const int yb = 2 * pyid[gi] - 1;
    const int xb = 2 * pxid[gi] - 1;
    const int t   = threadIdx.x;
    const int pix = t >> 4;              // 0..15
    const int seg = t & 15;              // 16 ushorts each
    const int py = pix >> 2, px = pix & 3;
    const int y = yb + py, x = xb + px;
    const int o = (py >> 1) + 2 * (px >> 1);   // samp order (0,0),(K,0),(0,K),(K,K)
    const int p = (py & 1) * 2 + (px & 1);
    const bool ok = ((unsigned)y < 128u) && ((unsigned)x < 128u);
    uint4 v0 = {0, 0, 0, 0}, v1 = {0, 0, 0, 0};
    if (ok) {
        const unsigned short* src = imgT + (((size_t)bi * 128 + y) * 128 + x) * 256 + seg * 16;
        v0 = *(const uint4*)(src);
        v1 = *(const uint4*)(src + 8);
    }
    unsigned short* dst = Abf + ((size_t)(b * 4 + o) * 512 + n) * 1024 + p * 256 + seg * 16;
    *(uint4*)(dst)     = v0;
    *(uint4*)(dst + 8) = v1;
}

// ---------------- Stage 3: bf16 MFMA GEMM (unchanged structure) ----------------
__global__ __launch_bounds__(256)
void gemm_kernel(const unsigned short* __restrict__ Wp,
                 const unsigned short* __restrict__ Abf,
                 const float* __restrict__ bias,
                 float* __restrict__ out) {
    const int orig = blockIdx.x;                    // 1024
    const int wg = (orig & 7) * 128 + (orig >> 3);  // bijective XCD swizzle
    const int et = wg & 7;
    const int nt = wg >> 3;
    const int g  = nt >> 2;
    const int n0 = (nt & 3) * 128;
    const int e0 = et * 128;

    const int tid  = threadIdx.x;
    const int lane = tid & 63;
    const int wid  = tid >> 6;
    const int wr   = wid >> 1;
    const int wc   = wid & 1;

    __shared__ unsigned short sW[128 * 64];
    __shared__ unsigned short sA[128 * 64];

    const f32x4 fzero = {0.f, 0.f, 0.f, 0.f};
    f32x4 acc[4][4];
    #pragma unroll
    for (int m = 0; m < 4; ++m)
        #pragma unroll
        for (int nf = 0; nf < 4; ++nf) acc[m][nf] = fzero;

    const size_t wrow_base = (size_t)e0 * 1024;
    const size_t arow_base = ((size_t)g * 512 + n0) * 1024;

    for (int kc = 0; kc < 16; ++kc) {
        if (kc) __syncthreads();
        const int kbase = kc * 64;
        #pragma unroll
        for (int r = 0; r < 4; ++r) {
            const int i   = r * 256 + tid;
            const int row = i >> 3;
            const int cl  = i & 7;
            const int cg  = cl ^ (row & 7);
            const unsigned short* gw = Wp + wrow_base + (size_t)row * 1024 + kbase + cg * 8;
            __builtin_amdgcn_global_load_lds(GAS(gw), LAS(&sW[i * 8]), 16, 0, 0);
            const unsigned short* ga = Abf + arow_base + (size_t)row * 1024 + kbase + cg * 8;
            __builtin_amdgcn_global_load_lds(GAS(ga), LAS(&sA[i * 8]), 16, 0, 0);
        }
        asm volatile("s_waitcnt vmcnt(0)" ::: "memory");
        __syncthreads();

        #pragma unroll
        for (int ks = 0; ks < 2; ++ks) {
            bf16x8 af[4], bfr[4];
            #pragma unroll
            for (int m = 0; m < 4; ++m) {
                const int row = wr * 64 + m * 16 + (lane & 15);
                const int cgc = ks * 4 + (lane >> 4);
                const int cl  = cgc ^ (row & 7);
                af[m] = *(const bf16x8*)&sW[row * 64 + cl * 8];
            }
            #pragma unroll
            for (int nf = 0; nf < 4; ++nf) {
                const int row = wc * 64 + nf * 16 + (lane & 15);
                const int cgc = ks * 4 + (lane >> 4);
                const int cl  = cgc ^ (row & 7);
                bfr[nf] = *(const bf16x8*)&sA[row * 64 + cl * 8];
            }
            #pragma unroll
            for (int m = 0; m < 4; ++m)
                #pragma unroll
                for (int nf = 0; nf < 4; ++nf)
                    acc[m][nf] = __builtin_amdgcn_mfma_f32_16x16x32_bf16(
                        af[m], bfr[nf], acc[m][nf], 0, 0, 0);
        }
    }

    const int erow_l = (lane >> 4) * 4;
    const int ncol_l = lane & 15;
    #pragma unroll
    for (int m = 0; m < 4; ++m) {
        #pragma unroll
        for (int nf = 0; nf < 4; ++nf) {
            const int nn = n0 + wc * 64 + nf * 16 + ncol_l;
            #pragma unroll
            for (int reg = 0; reg < 4; ++reg) {
                const int e = e0 + wr * 64 + m * 16 + erow_l + reg;
                out[((size_t)g * 1024 + e) * 512 + nn] = acc[m][nf][reg] + bias[e];
            }
        }
    }
}

extern "C" void kernel_launch(void* const* d_in, const int* in_sizes, int n_in,
                              void* d_out, int out_size, void* d_ws, size_t ws_size,
                              hipStream_t stream) {
    const float* img  = (const float*)d_in[0];
    const float* Wf   = (const float*)d_in[1];
    const float* bias = (const float*)d_in[2];
    const int*   bidx = (const int*)d_in[3];
    const int*   pxid = (const int*)d_in[4];
    const int*   pyid = (const int*)d_in[5];
    float* out = (float*)d_out;

    unsigned short* Abf  = (unsigned short*)d_ws;                          // 32 MiB @ 0
    unsigned short* Wp   = (unsigned short*)((char*)d_ws + (32u << 20));   // 2 MiB
    unsigned short* imgT = (unsigned short*)((char*)d_ws + (64u << 20));   // 64 MiB

    hipLaunchKernelGGL(wconv_kernel, dim3(1024), dim3(256), 0, stream, Wf, Wp);
    hipLaunchKernelGGL(imgt_kernel, dim3(4096), dim3(256), 0, stream, img, imgT);
    hipLaunchKernelGGL(gather_kernel, dim3(4096), dim3(256), 0, stream,
                       imgT, bidx, pxid, pyid, Abf);
    hipLaunchKernelGGL(gemm_kernel, dim3(1024), dim3(256), 0, stream,
                       Wp, Abf, bias, out);
}

// Round 5
// 84.010 us; speedup vs baseline: 11.6319x; 1.2219x over previous
//
#include <hip/hip_runtime.h>
#include <stdint.h>

// Pipeline (k' = (ky*2+kx)*256 + c ordering for the GEMM K axis):
//   0. wconv : W (1024,256,2,2) fp32 -> Wp[e][p*256+c] bf16 (2 MiB) + 512B zero page
//   1. imgt  : img (8,256,128,128) fp32 -> imgT[b][y][x][c] bf16 (64 MiB)
//   2. gemm  : 256x256-tile 8-wave MFMA GEMM, A gathered in-staging from imgT
//              out[(g*1024+e)][n] = sum_k' Wp[e][k'] * A[g][n][k'] + bias[e]
//      pixel (py,px) <-> (o,p): o=(py>>1)+2*(px>>1), p=(py&1)*2+(px&1)

typedef __attribute__((ext_vector_type(8))) short bf16x8;
typedef __attribute__((ext_vector_type(4))) float f32x4;

#define GAS(p) ((const __attribute__((address_space(1))) void*)(p))
#define LAS(p) ((__attribute__((address_space(3))) void*)(p))

__device__ __forceinline__ unsigned short f2bf(float f) {
    union { float f; uint32_t u; } x; x.f = f;
    uint32_t u = x.u;
    uint32_t r = (u + 0x7FFFu + ((u >> 16) & 1u)) >> 16;   // round-nearest-even
    return (unsigned short)r;
}

// ---------------- Stage 0: W reorder fp32 -> bf16 (+ zero page) ----------------
__global__ __launch_bounds__(256)
void wconv_kernel(const float* __restrict__ Wf, unsigned short* __restrict__ Wp,
                  unsigned short* __restrict__ zp) {
    const int e = blockIdx.x;            // 1024
    const int c = threadIdx.x;           // 256
    float4 w4 = *(const float4*)&Wf[(size_t)e * 1024 + c * 4];
    Wp[e * 1024 + 0 * 256 + c] = f2bf(w4.x);
    Wp[e * 1024 + 1 * 256 + c] = f2bf(w4.y);
    Wp[e * 1024 + 2 * 256 + c] = f2bf(w4.z);
    Wp[e * 1024 + 3 * 256 + c] = f2bf(w4.w);
    if (e == 0 && c < 32) {
        uint4 z = {0, 0, 0, 0};
        ((uint4*)zp)[c] = z;             // 512 B of zeros for OOB staging
    }
}

// ---------------- Stage 1: img -> imgT[b][y][x][c] bf16 ----------------
__global__ __launch_bounds__(256)
void imgt_kernel(const float* __restrict__ img, unsigned short* __restrict__ imgT) {
    const int blk = blockIdx.x;          // 4096
    const int cc = blk & 3;
    const int y  = (blk >> 2) & 127;
    const int b  = blk >> 9;
    __shared__ unsigned short sT[8192];  // [x:128][c:64] swizzled, 16 KB
    const int t  = threadIdx.x;
    const int x  = t & 127;
    const int ah = t >> 7;               // 0..1
    const size_t ibase = ((size_t)b * 256 + cc * 64) * 16384 + (size_t)y * 128 + x;
    #pragma unroll
    for (int it = 0; it < 16; ++it) {
        const int a = ah + 2 * it;       // c-pair 0..31
        const float v0 = img[ibase + (size_t)(2 * a)     * 16384];
        const float v1 = img[ibase + (size_t)(2 * a + 1) * 16384];
        const unsigned int pk = (unsigned)f2bf(v0) | ((unsigned)f2bf(v1) << 16);
        *(unsigned int*)&sT[x * 64 + ((2 * a) ^ (2 * (x & 31)))] = pk;
    }
    __syncthreads();
    unsigned short* ob = imgT + (((size_t)b * 128 + y) * 128) * 256 + cc * 64;
    #pragma unroll
    for (int jj = 0; jj < 16; ++jj) {
        const int o  = t + 256 * jj;     // 0..4095
        const int xx = o >> 5;
        const int c2 = o & 31;
        const unsigned int pk = *(const unsigned int*)&sT[xx * 64 + 2 * (c2 ^ (xx & 31))];
        *(unsigned int*)&ob[(size_t)xx * 256 + c2 * 2] = pk;
    }
}

// ---------------- Stage 2: fused-gather 256^2 MFMA GEMM ----------------
// Grid 256 blocks (1/CU), 512 threads (8 waves, 2m x 4n). BK=64, 16 K-tiles.
// LDS: 2 buffers x (W 32KB + A 32KB) = 128 KiB. XOR swizzle chunk^= (row&7).
__global__ __launch_bounds__(512, 2)
void gemm_kernel(const unsigned short* __restrict__ Wp,
                 const unsigned short* __restrict__ imgT,
                 const unsigned short* __restrict__ zp,
                 const int* __restrict__ bidx,
                 const int* __restrict__ pxid,
                 const int* __restrict__ pyid,
                 const float* __restrict__ bias,
                 float* __restrict__ out)
{
    const int i0   = blockIdx.x;          // 256
    const int xcd  = i0 & 7;
    const int slot = i0 >> 3;             // 0..31
    const int et   = slot & 3;            // 4 e-tiles of 256
    const int gnt  = xcd * 8 + (slot >> 2);  // 64 gn-tiles of 256; e-siblings share XCD
    const int e0   = et * 256;
    const int g    = gnt >> 1;            // tile lies within one g (512 n per g)
    const int nbase = (gnt & 1) * 256;
    const int b = g >> 2, o = g & 3;

    const int tid  = threadIdx.x;
    const int lane = tid & 63;
    const int wid  = tid >> 6;
    const int wm   = wid >> 2;            // 0..1 -> e rows wm*128
    const int wn   = wid & 3;             // 0..3 -> n cols wn*64

    __shared__ unsigned short smem[2][32768];   // [buf][ W:16384 | A:16384 ]

    // ---- per-thread stage descriptors (4 staging insts -> 4 rows each) ----
    const unsigned short* wsrc[4];
    size_t aplane[4];
    int ay[4], ax[4], cgr[4];
    #pragma unroll
    for (int r = 0; r < 4; ++r) {
        const int i   = r * 512 + tid;
        const int row = i >> 3;           // 0..255 (e-row for W, n-row for A)
        const int cg  = (i & 7) ^ (row & 7);
        cgr[r] = cg;
        wsrc[r] = Wp + (size_t)(e0 + row) * 1024 + cg * 8;
        const int gi = b * 512 + nbase + row;
        const int bi = bidx[gi];
        ay[r] = 2 * pyid[gi] - 1 + (o & 1) * 2;   // + (p>>1)
        ax[r] = 2 * pxid[gi] - 1 + (o >> 1) * 2;  // + (p&1)
        aplane[r] = (size_t)bi * (128 * 128 * 256);
    }

    f32x4 acc[8][4];
    #pragma unroll
    for (int m = 0; m < 8; ++m)
        #pragma unroll
        for (int nf = 0; nf < 4; ++nf) acc[m][nf] = (f32x4){0.f, 0.f, 0.f, 0.f};

    // ---- staging: one K-tile (kc) into buffer buf ----
    auto stage = [&](int kc, int buf) {
        const int p   = kc >> 2;
        const int csh = (kc & 3) * 64;    // short offset of c-chunk within pixel row
        unsigned short* sW = &smem[buf][0];
        unsigned short* sA = &smem[buf][16384];
        #pragma unroll
        for (int r = 0; r < 4; ++r) {
            const int i = r * 512 + tid;
            __builtin_amdgcn_global_load_lds(GAS(wsrc[r] + kc * 64), LAS(&sW[i * 8]), 16, 0, 0);
            const int y = ay[r] + (p >> 1);
            const int x = ax[r] + (p & 1);
            const unsigned short* asrc;
            if ((unsigned)y < 128u && (unsigned)x < 128u)
                asrc = imgT + aplane[r] + ((size_t)(y * 128 + x)) * 256 + csh + cgr[r] * 8;
            else
                asrc = zp + cgr[r] * 8;   // zeros
            __builtin_amdgcn_global_load_lds(GAS(asrc), LAS(&sA[i * 8]), 16, 0, 0);
        }
    };

    stage(0, 0);
    asm volatile("s_waitcnt vmcnt(0)" ::: "memory");
    __syncthreads();

    for (int kt = 0; kt < 16; ++kt) {
        const int cur = kt & 1;
        if (kt < 15) stage(kt + 1, cur ^ 1);      // issue early, drain at iter end
        const unsigned short* sW = &smem[cur][0];
        const unsigned short* sA = &smem[cur][16384];

        #pragma unroll
        for (int ph = 0; ph < 4; ++ph) {          // quadrant: 4 m-frags x 2 n-frags
            const int mb = (ph >> 1) * 4;
            const int nb = (ph & 1) * 2;
            bf16x8 af[4][2], bfr[2][2];
            #pragma unroll
            for (int mm = 0; mm < 4; ++mm) {
                const int row = wm * 128 + (mb + mm) * 16 + (lane & 15);
                #pragma unroll
                for (int ks = 0; ks < 2; ++ks) {
                    const int cl = (ks * 4 + (lane >> 4)) ^ (row & 7);
                    af[mm][ks] = *(const bf16x8*)&sW[row * 64 + cl * 8];
                }
            }
            #pragma unroll
            for (int nn = 0; nn < 2; ++nn) {
                const int row = wn * 64 + (nb + nn) * 16 + (lane & 15);
                #pragma unroll
                for (int ks = 0; ks < 2; ++ks) {
                    const int cl = (ks * 4 + (lane >> 4)) ^ (row & 7);
                    bfr[nn][ks] = *(const bf16x8*)&sA[row * 64 + cl * 8];
                }
            }
            __builtin_amdgcn_s_setprio(1);
            #pragma unroll
            for (int mm = 0; mm < 4; ++mm)
                #pragma unroll
                for (int nn = 0; nn < 2; ++nn)
                    #pragma unroll
                    for (int ks = 0; ks < 2; ++ks)
                        acc[mb + mm][nb + nn] = __builtin_amdgcn_mfma_f32_16x16x32_bf16(
                            af[mm][ks], bfr[nn][ks], acc[mb + mm][nb + nn], 0, 0, 0);
            __builtin_amdgcn_s_setprio(0);
            if (ph < 3) __builtin_amdgcn_s_barrier();
        }
        asm volatile("s_waitcnt vmcnt(0)" ::: "memory");
        __syncthreads();
    }

    // ---- epilogue: D row(e) = (lane>>4)*4+reg, col(n) = lane&15 ----
    #pragma unroll
    for (int m = 0; m < 8; ++m) {
        #pragma unroll
        for (int nf = 0; nf < 4; ++nf) {
            const int nl = nbase + wn * 64 + nf * 16 + (lane & 15);
            #pragma unroll
            for (int reg = 0; reg < 4; ++reg) {
                const int e = e0 + wm * 128 + m * 16 + (lane >> 4) * 4 + reg;
                out[((size_t)g * 1024 + e) * 512 + nl] = acc[m][nf][reg] + bias[e];
            }
        }
    }
}

extern "C" void kernel_launch(void* const* d_in, const int* in_sizes, int n_in,
                              void* d_out, int out_size, void* d_ws, size_t ws_size,
                              hipStream_t stream) {
    const float* img  = (const float*)d_in[0];
    const float* Wf   = (const float*)d_in[1];
    const float* bias = (const float*)d_in[2];
    const int*   bidx = (const int*)d_in[3];
    const int*   pxid = (const int*)d_in[4];
    const int*   pyid = (const int*)d_in[5];
    float* out = (float*)d_out;

    unsigned short* Wp   = (unsigned short*)((char*)d_ws + (32u << 20));  // 2 MiB
    unsigned short* zp   = (unsigned short*)((char*)d_ws + (36u << 20));  // 512 B zeros
    unsigned short* imgT = (unsigned short*)((char*)d_ws + (64u << 20));  // 64 MiB

    hipLaunchKernelGGL(wconv_kernel, dim3(1024), dim3(256), 0, stream, Wf, Wp, zp);
    hipLaunchKernelGGL(imgt_kernel, dim3(4096), dim3(256), 0, stream, img, imgT);
    hipLaunchKernelGGL(gemm_kernel, dim3(256), dim3(512), 0, stream,
                       Wp, imgT, zp, bidx, pxid, pyid, bias, out);
}

// Round 6
// 81.669 us; speedup vs baseline: 11.9654x; 1.0287x over previous
//
#include <hip/hip_runtime.h>
#include <stdint.h>

// Pipeline (k' = (ky*2+kx)*256 + c ordering for the GEMM K axis):
//   0. prep : blocks 0..1023  -> W (1024,256,2,2) fp32 -> Wp[e][p*256+c] bf16 + zero page
//             blocks 1024..5119 -> img (8,256,128,128) fp32 -> imgT[b][y][x][c] bf16
//   1. gemm : 128x128-tile 4-wave MFMA GEMM (R3-measured structure), A gathered
//             in-staging per keypoint from imgT; out = W'·A + bias
//      pixel (py,px) <-> (o,p): o=(py>>1)+2*(px>>1), p=(py&1)*2+(px&1)

typedef __attribute__((ext_vector_type(8))) short bf16x8;
typedef __attribute__((ext_vector_type(4))) float f32x4;

#define GAS(p) ((const __attribute__((address_space(1))) void*)(p))
#define LAS(p) ((__attribute__((address_space(3))) void*)(p))

__device__ __forceinline__ unsigned short f2bf(float f) {
    union { float f; uint32_t u; } x; x.f = f;
    uint32_t u = x.u;
    uint32_t r = (u + 0x7FFFu + ((u >> 16) & 1u)) >> 16;   // round-nearest-even
    return (unsigned short)r;
}

// ---------------- Stage 0: fused W-reorder + img transpose ----------------
__global__ __launch_bounds__(256)
void prep_kernel(const float* __restrict__ img, const float* __restrict__ Wf,
                 unsigned short* __restrict__ Wp, unsigned short* __restrict__ zp,
                 unsigned short* __restrict__ imgT) {
    __shared__ unsigned short sT[8192];
    const int blk = blockIdx.x;
    const int t = threadIdx.x;

    if (blk < 1024) {                     // ---- wconv: e = blk, c = t ----
        const int e = blk, c = t;
        float4 w4 = *(const float4*)&Wf[(size_t)e * 1024 + c * 4];
        Wp[e * 1024 + 0 * 256 + c] = f2bf(w4.x);   // p = ky*2+kx
        Wp[e * 1024 + 1 * 256 + c] = f2bf(w4.y);
        Wp[e * 1024 + 2 * 256 + c] = f2bf(w4.z);
        Wp[e * 1024 + 3 * 256 + c] = f2bf(w4.w);
        if (e == 0 && c < 32) {
            uint4 z = {0, 0, 0, 0};
            ((uint4*)zp)[c] = z;          // 512 B zeros for OOB staging
        }
        return;
    }

    // ---- imgt: block = (b, y, c-chunk of 64) ----
    const int ib = blk - 1024;            // 0..4095
    const int cc = ib & 3;
    const int y  = (ib >> 2) & 127;
    const int b  = ib >> 9;
    const int x  = t & 127;
    const int ah = t >> 7;                // 0..1
    const size_t ibase = ((size_t)b * 256 + cc * 64) * 16384 + (size_t)y * 128 + x;
    #pragma unroll
    for (int it = 0; it < 16; ++it) {
        const int a = ah + 2 * it;        // c-pair 0..31
        const float v0 = img[ibase + (size_t)(2 * a)     * 16384];
        const float v1 = img[ibase + (size_t)(2 * a + 1) * 16384];
        const unsigned int pk = (unsigned)f2bf(v0) | ((unsigned)f2bf(v1) << 16);
        *(unsigned int*)&sT[x * 64 + ((2 * a) ^ (2 * (x & 31)))] = pk;
    }
    __syncthreads();
    unsigned short* ob = imgT + (((size_t)b * 128 + y) * 128) * 256 + cc * 64;
    #pragma unroll
    for (int jj = 0; jj < 16; ++jj) {
        const int oo = t + 256 * jj;      // 0..4095
        const int xx = oo >> 5;
        const int c2 = oo & 31;
        const unsigned int pk = *(const unsigned int*)&sT[xx * 64 + 2 * (c2 ^ (xx & 31))];
        *(unsigned int*)&ob[(size_t)xx * 256 + c2 * 2] = pk;
    }
}

// ---------------- Stage 1: fused-gather 128^2 MFMA GEMM (R3 structure) ----------------
// 1024 blocks, 256 threads (4 waves 2x2), BK=64, 16 K-tiles, 32 KB LDS -> 4 blocks/CU.
// LDS [128 rows][8 x 16B chunks], XOR swizzle folded into the global SOURCE address.
__global__ __launch_bounds__(256)
void gemm_kernel(const unsigned short* __restrict__ Wp,
                 const unsigned short* __restrict__ imgT,
                 const unsigned short* __restrict__ zp,
                 const int* __restrict__ bidx,
                 const int* __restrict__ pxid,
                 const int* __restrict__ pyid,
                 const float* __restrict__ bias,
                 float* __restrict__ out) {
    const int orig = blockIdx.x;                    // 1024
    const int wg = (orig & 7) * 128 + (orig >> 3);  // bijective XCD swizzle
    const int et = wg & 7;                          // 8 e-tiles of 128
    const int nt = wg >> 3;                         // 128 gn-tiles of 128
    const int g  = nt >> 2;
    const int n0 = (nt & 3) * 128;
    const int e0 = et * 128;
    const int b = g >> 2, o = g & 3;

    const int tid  = threadIdx.x;
    const int lane = tid & 63;
    const int wid  = tid >> 6;
    const int wr   = wid >> 1;
    const int wc   = wid & 1;

    __shared__ unsigned short sW[128 * 64];
    __shared__ unsigned short sA[128 * 64];

    // ---- per-thread stage descriptors: rows row0+32r, same chunk cg for all r ----
    const int row0 = tid >> 3;                      // 0..31
    const int cg   = (tid & 7) ^ (row0 & 7);        // (row&7) == (row0&7) since 32r%8==0
    int ay[4], ax[4];
    size_t apl[4];
    #pragma unroll
    for (int r = 0; r < 4; ++r) {
        const int row = row0 + 32 * r;
        const int gi = b * 512 + n0 + row;
        apl[r] = (size_t)bidx[gi] * (128 * 128 * 256);
        ay[r] = 2 * pyid[gi] - 1 + (o & 1) * 2;     // + (p>>1) at stage time
        ax[r] = 2 * pxid[gi] - 1 + (o >> 1) * 2;    // + (p&1)
    }

    const f32x4 fzero = {0.f, 0.f, 0.f, 0.f};
    f32x4 acc[4][4];
    #pragma unroll
    for (int m = 0; m < 4; ++m)
        #pragma unroll
        for (int nf = 0; nf < 4; ++nf) acc[m][nf] = fzero;

    for (int kc = 0; kc < 16; ++kc) {
        if (kc) __syncthreads();
        const int p   = kc >> 2;
        const int csh = (kc & 3) * 64;              // c-chunk offset within pixel row
        const int y   = 0;
        (void)y;
        #pragma unroll
        for (int r = 0; r < 4; ++r) {
            const int i   = r * 256 + tid;
            const int row = row0 + 32 * r;
            const unsigned short* gw = Wp + (size_t)(e0 + row) * 1024 + kc * 64 + cg * 8;
            __builtin_amdgcn_global_load_lds(GAS(gw), LAS(&sW[i * 8]), 16, 0, 0);
            const int yy = ay[r] + (p >> 1);
            const int xx = ax[r] + (p & 1);
            const unsigned short* ga =
                ((unsigned)yy < 128u && (unsigned)xx < 128u)
                    ? imgT + apl[r] + ((size_t)(yy * 128 + xx)) * 256 + csh + cg * 8
                    : zp + cg * 8;
            __builtin_amdgcn_global_load_lds(GAS(ga), LAS(&sA[i * 8]), 16, 0, 0);
        }
        asm volatile("s_waitcnt vmcnt(0)" ::: "memory");
        __syncthreads();

        #pragma unroll
        for (int ks = 0; ks < 2; ++ks) {
            bf16x8 af[4], bfr[4];
            #pragma unroll
            for (int m = 0; m < 4; ++m) {
                const int row = wr * 64 + m * 16 + (lane & 15);
                const int cl  = (ks * 4 + (lane >> 4)) ^ (row & 7);
                af[m] = *(const bf16x8*)&sW[row * 64 + cl * 8];
            }
            #pragma unroll
            for (int nf = 0; nf < 4; ++nf) {
                const int row = wc * 64 + nf * 16 + (lane & 15);
                const int cl  = (ks * 4 + (lane >> 4)) ^ (row & 7);
                bfr[nf] = *(const bf16x8*)&sA[row * 64 + cl * 8];
            }
            __builtin_amdgcn_s_setprio(1);
            #pragma unroll
            for (int m = 0; m < 4; ++m)
                #pragma unroll
                for (int nf = 0; nf < 4; ++nf)
                    acc[m][nf] = __builtin_amdgcn_mfma_f32_16x16x32_bf16(
                        af[m], bfr[nf], acc[m][nf], 0, 0, 0);
            __builtin_amdgcn_s_setprio(0);
        }
    }

    // ---- epilogue: D row(e) = (lane>>4)*4+reg, col(n) = lane&15 ----
    const int erow_l = (lane >> 4) * 4;
    const int ncol_l = lane & 15;
    #pragma unroll
    for (int m = 0; m < 4; ++m) {
        #pragma unroll
        for (int nf = 0; nf < 4; ++nf) {
            const int nn = n0 + wc * 64 + nf * 16 + ncol_l;
            #pragma unroll
            for (int reg = 0; reg < 4; ++reg) {
                const int e = e0 + wr * 64 + m * 16 + erow_l + reg;
                out[((size_t)g * 1024 + e) * 512 + nn] = acc[m][nf][reg] + bias[e];
            }
        }
    }
}

extern "C" void kernel_launch(void* const* d_in, const int* in_sizes, int n_in,
                              void* d_out, int out_size, void* d_ws, size_t ws_size,
                              hipStream_t stream) {
    const float* img  = (const float*)d_in[0];
    const float* Wf   = (const float*)d_in[1];
    const float* bias = (const float*)d_in[2];
    const int*   bidx = (const int*)d_in[3];
    const int*   pxid = (const int*)d_in[4];
    const int*   pyid = (const int*)d_in[5];
    float* out = (float*)d_out;

    unsigned short* Wp   = (unsigned short*)((char*)d_ws + (32u << 20));  // 2 MiB
    unsigned short* zp   = (unsigned short*)((char*)d_ws + (36u << 20));  // 512 B zeros
    unsigned short* imgT = (unsigned short*)((char*)d_ws + (64u << 20));  // 64 MiB

    hipLaunchKernelGGL(prep_kernel, dim3(5120), dim3(256), 0, stream,
                       img, Wf, Wp, zp, imgT);
    hipLaunchKernelGGL(gemm_kernel, dim3(1024), dim3(256), 0, stream,
                       Wp, imgT, zp, bidx, pxid, pyid, bias, out);
}